// Round 1
// baseline (3180.215 us; speedup 1.0000x reference)
//
#include <hip/hip_runtime.h>
#include <hip/hip_bf16.h>
#include <cstdint>
#include <cstddef>

// ---------------------------------------------------------------------------
// Transformer: L=8, B=8, N=1024, W=768, H=12, C=64.  h kept fp32 in d_out.
// All GEMMs bf16-MFMA (16x16x32), fp32 accum. LN/softmax/GELU fp32.
// ---------------------------------------------------------------------------

typedef __attribute__((ext_vector_type(8))) short bf16x8;   // 8 bf16 = 4 VGPRs
typedef __attribute__((ext_vector_type(4))) float f32x4;

#define MFMA16(a, b, c) __builtin_amdgcn_mfma_f32_16x16x32_bf16((a), (b), (c), 0, 0, 0)

__device__ __forceinline__ void gld_lds16(const void* g, void* l) {
    // async global->LDS, 16B per lane; LDS dest must be uniform_base + lane*16
    __builtin_amdgcn_global_load_lds((const __attribute__((address_space(1))) unsigned int*)g,
                                     (__attribute__((address_space(3))) unsigned int*)l,
                                     16, 0, 0);
}

__device__ __forceinline__ short f32_to_bf16_bits(float f) {
    unsigned u = __builtin_bit_cast(unsigned, f);
    u += 0x7fffu + ((u >> 16) & 1u);      // RNE; inputs are finite
    return (short)(u >> 16);
}

// ---------------------------------------------------------------------------
// GEMM: C[M,N] = A[M,K](bf16) @ Bt[N,K]^T(bf16) + bias; optional residual(fp32,
// in-place ok), exact GELU, fp32 and/or bf16 outputs.  M,N % 128 == 0, K % 32 == 0.
// m97 structure: 128x128 tile, BK=32, 4 waves each 64x64 (4x4 MFMA tiles).
// ---------------------------------------------------------------------------
template <bool RES, bool GELU, bool WF, bool WH>
__global__ __launch_bounds__(256) void gemm_bt(const __hip_bfloat16* __restrict__ A,
                                               const __hip_bfloat16* __restrict__ Bt,
                                               const float* __restrict__ bias,
                                               const float* __restrict__ res,
                                               float* __restrict__ outf,
                                               __hip_bfloat16* __restrict__ outh,
                                               int M, int N, int K) {
    __shared__ __hip_bfloat16 lA[128 * 32];
    __shared__ __hip_bfloat16 lB[128 * 32];
    const int t = threadIdx.x;
    const int w = t >> 6, l = t & 63;
    const int lr = l & 15, lg = l >> 4;
    const int m0 = blockIdx.y * 128, n0 = blockIdx.x * 128;
    const int wm = (w & 1) * 64, wn = (w >> 1) * 64;

    f32x4 acc[4][4];
#pragma unroll
    for (int i = 0; i < 4; i++)
#pragma unroll
        for (int j = 0; j < 4; j++) acc[i][j] = (f32x4){0.f, 0.f, 0.f, 0.f};

    for (int k0 = 0; k0 < K; k0 += 32) {
        __syncthreads();
#pragma unroll
        for (int i = 0; i < 2; i++) {
            int c = t + i * 256;            // 512 chunks of 16B per 8KB tile
            int row = c >> 2, seg = c & 3;  // row-major [128][32] bf16
            gld_lds16(&A[(size_t)(m0 + row) * K + k0 + seg * 8], &lA[c * 8]);
            gld_lds16(&Bt[(size_t)(n0 + row) * K + k0 + seg * 8], &lB[c * 8]);
        }
        __syncthreads();
        bf16x8 af[4], bfr[4];
#pragma unroll
        for (int mt = 0; mt < 4; mt++)
            af[mt] = *(const bf16x8*)&lA[(wm + mt * 16 + lr) * 32 + lg * 8];
#pragma unroll
        for (int nt = 0; nt < 4; nt++)
            bfr[nt] = *(const bf16x8*)&lB[(wn + nt * 16 + lr) * 32 + lg * 8];
#pragma unroll
        for (int mt = 0; mt < 4; mt++)
#pragma unroll
            for (int nt = 0; nt < 4; nt++)
                acc[mt][nt] = MFMA16(af[mt], bfr[nt], acc[mt][nt]);
    }

    // epilogue: C/D layout col=lane&15, row=(lane>>4)*4+reg  [m89/m91 verified]
#pragma unroll
    for (int nt = 0; nt < 4; nt++) {
        const int col = n0 + wn + nt * 16 + lr;
        const float bv = bias[col];
#pragma unroll
        for (int mt = 0; mt < 4; mt++) {
#pragma unroll
            for (int r = 0; r < 4; r++) {
                const int row = m0 + wm + mt * 16 + lg * 4 + r;
                const size_t idx = (size_t)row * N + col;
                float v = acc[mt][nt][r] + bv;
                if (RES) v += res[idx];
                if (GELU) v = 0.5f * v * (1.f + erff(v * 0.70710678118654752f));
                if (WF) outf[idx] = v;
                if (WH) outh[idx] = __float2bfloat16(v);
            }
        }
    }
}

// ---------------------------------------------------------------------------
// LayerNorm over W=768: one block per row, fp32 in, bf16 out (affine).
// ---------------------------------------------------------------------------
__global__ __launch_bounds__(256) void ln_kernel(const float* __restrict__ h,
                                                 const float* __restrict__ g,
                                                 const float* __restrict__ b,
                                                 __hip_bfloat16* __restrict__ y) {
    const int row = blockIdx.x;
    const int t = threadIdx.x;
    const float* hr = h + (size_t)row * 768;
    float x0 = hr[t], x1 = hr[t + 256], x2 = hr[t + 512];
    float s = x0 + x1 + x2;
    float q = x0 * x0 + x1 * x1 + x2 * x2;
#pragma unroll
    for (int d = 1; d < 64; d <<= 1) {
        s += __shfl_xor(s, d);
        q += __shfl_xor(q, d);
    }
    __shared__ float red[8];
    const int w = t >> 6, l = t & 63;
    if (l == 0) { red[w] = s; red[w + 4] = q; }
    __syncthreads();
    s = red[0] + red[1] + red[2] + red[3];
    q = red[4] + red[5] + red[6] + red[7];
    const float mean = s * (1.f / 768.f);
    const float var = q * (1.f / 768.f) - mean * mean;
    const float rs = rsqrtf(var + 1e-5f);
    __hip_bfloat16* yr = y + (size_t)row * 768;
    yr[t]       = __float2bfloat16((x0 - mean) * rs * g[t] + b[t]);
    yr[t + 256] = __float2bfloat16((x1 - mean) * rs * g[t + 256] + b[t + 256]);
    yr[t + 512] = __float2bfloat16((x2 - mean) * rs * g[t + 512] + b[t + 512]);
}

// ---------------------------------------------------------------------------
// Per-layer weight transpose+convert: W[K,N] fp32 -> Wt[N,K] bf16 (4 matrices).
// ---------------------------------------------------------------------------
__global__ __launch_bounds__(256) void transpose_weights(const float* __restrict__ sq,
                                                         const float* __restrict__ so,
                                                         const float* __restrict__ sf,
                                                         const float* __restrict__ sp,
                                                         __hip_bfloat16* __restrict__ dq,
                                                         __hip_bfloat16* __restrict__ dO,
                                                         __hip_bfloat16* __restrict__ df,
                                                         __hip_bfloat16* __restrict__ dp) {
    const int bid = blockIdx.x;
    const float* src;
    __hip_bfloat16* dst;
    int K, N, tloc;
    if (bid < 1728)      { src = sq; dst = dq; K = 768;  N = 2304; tloc = bid; }
    else if (bid < 2304) { src = so; dst = dO; K = 768;  N = 768;  tloc = bid - 1728; }
    else if (bid < 4608) { src = sf; dst = df; K = 768;  N = 3072; tloc = bid - 2304; }
    else                 { src = sp; dst = dp; K = 3072; N = 768;  tloc = bid - 4608; }
    const int ktiles = K / 32;
    const int k0 = (tloc % ktiles) * 32;
    const int n0 = (tloc / ktiles) * 32;
    const int t = threadIdx.x;
    __shared__ float tile[32][33];
#pragma unroll
    for (int p = 0; p < 4; p++) {
        int rr = p * 8 + (t >> 5);
        tile[rr][t & 31] = src[(size_t)(k0 + rr) * N + n0 + (t & 31)];
    }
    __syncthreads();
#pragma unroll
    for (int p = 0; p < 4; p++) {
        int rr = p * 8 + (t >> 5);
        dst[(size_t)(n0 + rr) * K + k0 + (t & 31)] = __float2bfloat16(tile[t & 31][rr]);
    }
}

// ---------------------------------------------------------------------------
// V transpose: qkv[b,n, h*192+128+c] -> vt[(b*12+h)*64+c, n]   (bf16 bits)
// ---------------------------------------------------------------------------
__global__ __launch_bounds__(256) void vt_transpose(const short* __restrict__ qkv,
                                                    short* __restrict__ vt) {
    const int bid = blockIdx.x;           // 96 bh * 64 tiles
    const int bh = bid >> 6, tau = bid & 63;
    const int b = bh / 12, h = bh % 12;
    const int ct = tau >> 5, nt = tau & 31;
    const int n0 = nt * 32, c0 = ct * 32;
    const int t = threadIdx.x;
    __shared__ short tile[32][33];
    const short* base = qkv + (size_t)(b * 1024 + n0) * 2304 + h * 192 + 128 + c0;
#pragma unroll
    for (int p = 0; p < 4; p++) {
        int rr = p * 8 + (t >> 5);
        tile[rr][t & 31] = base[(size_t)rr * 2304 + (t & 31)];
    }
    __syncthreads();
    short* ob = vt + (size_t)((b * 12 + h) * 64 + c0) * 1024 + n0;
#pragma unroll
    for (int p = 0; p < 4; p++) {
        int rr = p * 8 + (t >> 5);
        ob[(size_t)rr * 1024 + (t & 31)] = tile[t & 31][rr];
    }
}

// ---------------------------------------------------------------------------
// Flash attention: workgroup = (64 queries, head, batch); 4 waves x 16 rows.
// S and O in MFMA C-layout; P routed through per-wave LDS (C->A layout).
// Score scale 1/8 (= scale^2 of reference, C=64).
// ---------------------------------------------------------------------------
__global__ __launch_bounds__(256) void attn_kernel(const short* __restrict__ qkv,
                                                   const short* __restrict__ vt,
                                                   short* __restrict__ attnout) {
    const int qt = blockIdx.x, hh = blockIdx.y, b = blockIdx.z;
    const int t = threadIdx.x, w = t >> 6, l = t & 63;
    const int lr = l & 15, lg = l >> 4;
    __shared__ short lK[64 * 72];          // [key][dim], stride 72 (pad)
    __shared__ short lV[64 * 72];          // [dim][key], stride 72 (pad)
    __shared__ short lP[4][16 * 64];       // per-wave P, [row][key]
    const int qw = qt * 64 + w * 16;

    // Q fragment (A-layout), loaded once from global
    bf16x8 aq[2];
#pragma unroll
    for (int ks = 0; ks < 2; ks++)
        aq[ks] = *(const bf16x8*)&qkv[(size_t)(b * 1024 + qw + lr) * 2304 + hh * 192 + ks * 32 + lg * 8];

    f32x4 o[4];
    float mr[4], lsum[4];
#pragma unroll
    for (int dt = 0; dt < 4; dt++) o[dt] = (f32x4){0.f, 0.f, 0.f, 0.f};
#pragma unroll
    for (int r = 0; r < 4; r++) { mr[r] = -3.0e38f; lsum[r] = 0.f; }

    for (int kt = 0; kt < 16; kt++) {
        const int key0 = kt * 64;
        __syncthreads();
#pragma unroll
        for (int i = 0; i < 2; i++) {
            int c = t + i * 256;
            int row = c >> 3, seg = c & 7;   // 64 rows x 8 chunks of 8 bf16
            *(bf16x8*)&lK[row * 72 + seg * 8] =
                *(const bf16x8*)&qkv[(size_t)(b * 1024 + key0 + row) * 2304 + hh * 192 + 64 + seg * 8];
            *(bf16x8*)&lV[row * 72 + seg * 8] =
                *(const bf16x8*)&vt[(size_t)((b * 12 + hh) * 64 + row) * 1024 + key0 + seg * 8];
        }
        __syncthreads();

        // S = Q K^T  (rows=queries, cols=keys)
        f32x4 s[4];
#pragma unroll
        for (int nt = 0; nt < 4; nt++) s[nt] = (f32x4){0.f, 0.f, 0.f, 0.f};
#pragma unroll
        for (int nt = 0; nt < 4; nt++)
#pragma unroll
            for (int ks = 0; ks < 2; ks++) {
                bf16x8 bk = *(const bf16x8*)&lK[(nt * 16 + lr) * 72 + ks * 32 + lg * 8];
                s[nt] = MFMA16(aq[ks], bk, s[nt]);
            }
#pragma unroll
        for (int nt = 0; nt < 4; nt++) s[nt] = s[nt] * 0.125f;

        // online softmax per row r (row = lg*4 + r); reduce over the 16-lane group
#pragma unroll
        for (int r = 0; r < 4; r++) {
            float mx = fmaxf(fmaxf(s[0][r], s[1][r]), fmaxf(s[2][r], s[3][r]));
            mx = fmaxf(mx, __shfl_xor(mx, 1));
            mx = fmaxf(mx, __shfl_xor(mx, 2));
            mx = fmaxf(mx, __shfl_xor(mx, 4));
            mx = fmaxf(mx, __shfl_xor(mx, 8));
            const float mn = fmaxf(mr[r], mx);
            const float al = expf(mr[r] - mn);
            mr[r] = mn;
            float ps = 0.f;
#pragma unroll
            for (int nt = 0; nt < 4; nt++) {
                float p = expf(s[nt][r] - mn);
                s[nt][r] = p;
                ps += p;
            }
            ps += __shfl_xor(ps, 1);
            ps += __shfl_xor(ps, 2);
            ps += __shfl_xor(ps, 4);
            ps += __shfl_xor(ps, 8);
            lsum[r] = lsum[r] * al + ps;
#pragma unroll
            for (int dt = 0; dt < 4; dt++) o[dt][r] *= al;
#pragma unroll
            for (int nt = 0; nt < 4; nt++)
                lP[w][(lg * 4 + r) * 64 + nt * 16 + lr] = f32_to_bf16_bits(s[nt][r]);
        }

        // O += P V   (P: A-layout from lP; V^T: B-operand from lV)
#pragma unroll
        for (int ks = 0; ks < 2; ks++) {
            bf16x8 ap = *(const bf16x8*)&lP[w][lr * 64 + ks * 32 + lg * 8];
#pragma unroll
            for (int dt = 0; dt < 4; dt++) {
                bf16x8 bv = *(const bf16x8*)&lV[(dt * 16 + lr) * 72 + ks * 32 + lg * 8];
                o[dt] = MFMA16(ap, bv, o[dt]);
            }
        }
    }

#pragma unroll
    for (int dt = 0; dt < 4; dt++)
#pragma unroll
        for (int r = 0; r < 4; r++)
            attnout[(size_t)(b * 1024 + qw + lg * 4 + r) * 768 + hh * 64 + dt * 16 + lr] =
                f32_to_bf16_bits(o[dt][r] / lsum[r]);
}

// ---------------------------------------------------------------------------
// Host
// ---------------------------------------------------------------------------
extern "C" void kernel_launch(void* const* d_in, const int* in_sizes, int n_in,
                              void* d_out, int out_size, void* d_ws, size_t ws_size,
                              hipStream_t stream) {
    const float* x    = (const float*)d_in[0];
    const float* Wqkv = (const float*)d_in[1];
    const float* bqkv = (const float*)d_in[2];
    const float* Wo   = (const float*)d_in[3];
    const float* bo   = (const float*)d_in[4];
    const float* Wfc  = (const float*)d_in[5];
    const float* bfc  = (const float*)d_in[6];
    const float* Wpr  = (const float*)d_in[7];
    const float* bpr  = (const float*)d_in[8];
    const float* g1   = (const float*)d_in[9];
    const float* b1   = (const float*)d_in[10];
    const float* g2   = (const float*)d_in[11];
    const float* b2   = (const float*)d_in[12];
    float* h = (float*)d_out;   // h lives in d_out throughout

    char* ws = (char*)d_ws;
    size_t off = 0;
    auto alloc = [&](size_t bytes) -> void* {
        void* p = ws + off;
        off += (bytes + 255) & ~(size_t)255;
        return p;
    };
    __hip_bfloat16* tQKV = (__hip_bfloat16*)alloc((size_t)2304 * 768 * 2);
    __hip_bfloat16* tO   = (__hip_bfloat16*)alloc((size_t)768 * 768 * 2);
    __hip_bfloat16* tFC  = (__hip_bfloat16*)alloc((size_t)3072 * 768 * 2);
    __hip_bfloat16* tPR  = (__hip_bfloat16*)alloc((size_t)768 * 3072 * 2);
    __hip_bfloat16* y    = (__hip_bfloat16*)alloc((size_t)8192 * 768 * 2);
    __hip_bfloat16* att  = (__hip_bfloat16*)alloc((size_t)8192 * 768 * 2);
    __hip_bfloat16* vtb  = (__hip_bfloat16*)alloc((size_t)8192 * 768 * 2);
    __hip_bfloat16* big  = (__hip_bfloat16*)alloc((size_t)8192 * 3072 * 2); // qkv & fc share
    __hip_bfloat16* qkvb = big;
    __hip_bfloat16* fcb  = big;

    hipMemcpyAsync(h, x, (size_t)8 * 1024 * 768 * 4, hipMemcpyDeviceToDevice, stream);

    for (int L = 0; L < 8; L++) {
        const float* wq = Wqkv + (size_t)L * 768 * 2304;
        const float* wo = Wo   + (size_t)L * 768 * 768;
        const float* wf = Wfc  + (size_t)L * 768 * 3072;
        const float* wp = Wpr  + (size_t)L * 3072 * 768;

        transpose_weights<<<6912, 256, 0, stream>>>(wq, wo, wf, wp, tQKV, tO, tFC, tPR);

        ln_kernel<<<8192, 256, 0, stream>>>(h, g1 + L * 768, b1 + L * 768, y);

        gemm_bt<false, false, false, true><<<dim3(18, 64), 256, 0, stream>>>(
            y, tQKV, bqkv + L * 2304, nullptr, nullptr, qkvb, 8192, 2304, 768);

        vt_transpose<<<6144, 256, 0, stream>>>((const short*)qkvb, (short*)vtb);

        attn_kernel<<<dim3(16, 12, 8), 256, 0, stream>>>(
            (const short*)qkvb, (const short*)vtb, (short*)att);

        gemm_bt<true, false, true, false><<<dim3(6, 64), 256, 0, stream>>>(
            att, tO, bo + L * 768, h, h, nullptr, 8192, 768, 768);

        ln_kernel<<<8192, 256, 0, stream>>>(h, g2 + L * 768, b2 + L * 768, y);

        gemm_bt<false, true, false, true><<<dim3(24, 64), 256, 0, stream>>>(
            y, tFC, bfc + L * 3072, nullptr, nullptr, fcb, 8192, 3072, 768);

        gemm_bt<true, false, true, false><<<dim3(6, 64), 256, 0, stream>>>(
            fcb, tPR, bpr + L * 768, h, h, nullptr, 8192, 768, 3072);
    }
}

// Round 2
// 2969.028 us; speedup vs baseline: 1.0711x; 1.0711x over previous
//
#include <hip/hip_runtime.h>
#include <hip/hip_bf16.h>
#include <cstdint>
#include <cstddef>

// ---------------------------------------------------------------------------
// Transformer: L=8, B=8, N=1024, W=768, H=12, C=64.  h kept fp32 in d_out.
// All GEMMs bf16-MFMA (16x16x32), fp32 accum. LN/softmax/GELU fp32.
// ---------------------------------------------------------------------------

typedef __attribute__((ext_vector_type(8))) short bf16x8;   // 8 bf16 = 4 VGPRs
typedef __attribute__((ext_vector_type(4))) float f32x4;

#define MFMA16(a, b, c) __builtin_amdgcn_mfma_f32_16x16x32_bf16((a), (b), (c), 0, 0, 0)

__device__ __forceinline__ void gld_lds16(const void* g, void* l) {
    // async global->LDS, 16B per lane; LDS dest must be uniform_base + lane*16
    __builtin_amdgcn_global_load_lds((const __attribute__((address_space(1))) unsigned int*)g,
                                     (__attribute__((address_space(3))) unsigned int*)l,
                                     16, 0, 0);
}

__device__ __forceinline__ unsigned short f32_to_bf16_bits(float f) {
    unsigned u = __builtin_bit_cast(unsigned, f);
    u += 0x7fffu + ((u >> 16) & 1u);      // RNE; inputs are finite
    return (unsigned short)(u >> 16);
}

__device__ __forceinline__ unsigned pack_bf2(float a, float b) {
    return (unsigned)f32_to_bf16_bits(a) | ((unsigned)f32_to_bf16_bits(b) << 16);
}

// ---------------------------------------------------------------------------
// GEMM: C[M,N] = A[M,K](bf16) @ Bt[N,K]^T(bf16) + bias; optional residual(fp32,
// in-place ok), exact GELU, fp32 and/or bf16 outputs.  M,N % 128 == 0, K % 32 == 0.
// m97 structure: 128x128 tile, BK=32, 4 waves each 64x64 (4x4 MFMA tiles).
// ---------------------------------------------------------------------------
template <bool RES, bool GELU, bool WF, bool WH>
__global__ __launch_bounds__(256) void gemm_bt(const __hip_bfloat16* __restrict__ A,
                                               const __hip_bfloat16* __restrict__ Bt,
                                               const float* __restrict__ bias,
                                               const float* __restrict__ res,
                                               float* __restrict__ outf,
                                               __hip_bfloat16* __restrict__ outh,
                                               int M, int N, int K) {
    __shared__ __hip_bfloat16 lA[128 * 32];
    __shared__ __hip_bfloat16 lB[128 * 32];
    const int t = threadIdx.x;
    const int w = t >> 6, l = t & 63;
    const int lr = l & 15, lg = l >> 4;
    const int m0 = blockIdx.y * 128, n0 = blockIdx.x * 128;
    const int wm = (w & 1) * 64, wn = (w >> 1) * 64;

    f32x4 acc[4][4];
#pragma unroll
    for (int i = 0; i < 4; i++)
#pragma unroll
        for (int j = 0; j < 4; j++) acc[i][j] = (f32x4){0.f, 0.f, 0.f, 0.f};

    for (int k0 = 0; k0 < K; k0 += 32) {
        __syncthreads();
#pragma unroll
        for (int i = 0; i < 2; i++) {
            int c = t + i * 256;            // 512 chunks of 16B per 8KB tile
            int row = c >> 2, seg = c & 3;  // row-major [128][32] bf16
            gld_lds16(&A[(size_t)(m0 + row) * K + k0 + seg * 8], &lA[c * 8]);
            gld_lds16(&Bt[(size_t)(n0 + row) * K + k0 + seg * 8], &lB[c * 8]);
        }
        __syncthreads();
        bf16x8 af[4], bfr[4];
#pragma unroll
        for (int mt = 0; mt < 4; mt++)
            af[mt] = *(const bf16x8*)&lA[(wm + mt * 16 + lr) * 32 + lg * 8];
#pragma unroll
        for (int nt = 0; nt < 4; nt++)
            bfr[nt] = *(const bf16x8*)&lB[(wn + nt * 16 + lr) * 32 + lg * 8];
#pragma unroll
        for (int mt = 0; mt < 4; mt++)
#pragma unroll
            for (int nt = 0; nt < 4; nt++)
                acc[mt][nt] = MFMA16(af[mt], bfr[nt], acc[mt][nt]);
    }

    // epilogue: C/D layout col=lane&15, row=(lane>>4)*4+reg  [m89/m91 verified]
#pragma unroll
    for (int nt = 0; nt < 4; nt++) {
        const int col = n0 + wn + nt * 16 + lr;
        const float bv = bias[col];
#pragma unroll
        for (int mt = 0; mt < 4; mt++) {
#pragma unroll
            for (int r = 0; r < 4; r++) {
                const int row = m0 + wm + mt * 16 + lg * 4 + r;
                const size_t idx = (size_t)row * N + col;
                float v = acc[mt][nt][r] + bv;
                if (RES) v += res[idx];
                if (GELU) v = 0.5f * v * (1.f + erff(v * 0.70710678118654752f));
                if (WF) outf[idx] = v;
                if (WH) outh[idx] = __float2bfloat16(v);
            }
        }
    }
}

// ---------------------------------------------------------------------------
// LayerNorm over W=768: one block per row, fp32 in, bf16 out (affine).
// ---------------------------------------------------------------------------
__global__ __launch_bounds__(256) void ln_kernel(const float* __restrict__ h,
                                                 const float* __restrict__ g,
                                                 const float* __restrict__ b,
                                                 __hip_bfloat16* __restrict__ y) {
    const int row = blockIdx.x;
    const int t = threadIdx.x;
    const float* hr = h + (size_t)row * 768;
    float x0 = hr[t], x1 = hr[t + 256], x2 = hr[t + 512];
    float s = x0 + x1 + x2;
    float q = x0 * x0 + x1 * x1 + x2 * x2;
#pragma unroll
    for (int d = 1; d < 64; d <<= 1) {
        s += __shfl_xor(s, d);
        q += __shfl_xor(q, d);
    }
    __shared__ float red[8];
    const int w = t >> 6, l = t & 63;
    if (l == 0) { red[w] = s; red[w + 4] = q; }
    __syncthreads();
    s = red[0] + red[1] + red[2] + red[3];
    q = red[4] + red[5] + red[6] + red[7];
    const float mean = s * (1.f / 768.f);
    const float var = q * (1.f / 768.f) - mean * mean;
    const float rs = rsqrtf(var + 1e-5f);
    __hip_bfloat16* yr = y + (size_t)row * 768;
    yr[t]       = __float2bfloat16((x0 - mean) * rs * g[t] + b[t]);
    yr[t + 256] = __float2bfloat16((x1 - mean) * rs * g[t + 256] + b[t + 256]);
    yr[t + 512] = __float2bfloat16((x2 - mean) * rs * g[t + 512] + b[t + 512]);
}

// ---------------------------------------------------------------------------
// Per-layer weight transpose+convert: W[K,N] fp32 -> Wt[N,K] bf16 (4 matrices).
// ---------------------------------------------------------------------------
__global__ __launch_bounds__(256) void transpose_weights(const float* __restrict__ sq,
                                                         const float* __restrict__ so,
                                                         const float* __restrict__ sf,
                                                         const float* __restrict__ sp,
                                                         __hip_bfloat16* __restrict__ dq,
                                                         __hip_bfloat16* __restrict__ dO,
                                                         __hip_bfloat16* __restrict__ df,
                                                         __hip_bfloat16* __restrict__ dp) {
    const int bid = blockIdx.x;
    const float* src;
    __hip_bfloat16* dst;
    int K, N, tloc;
    if (bid < 1728)      { src = sq; dst = dq; K = 768;  N = 2304; tloc = bid; }
    else if (bid < 2304) { src = so; dst = dO; K = 768;  N = 768;  tloc = bid - 1728; }
    else if (bid < 4608) { src = sf; dst = df; K = 768;  N = 3072; tloc = bid - 2304; }
    else                 { src = sp; dst = dp; K = 3072; N = 768;  tloc = bid - 4608; }
    const int ktiles = K / 32;
    const int k0 = (tloc % ktiles) * 32;
    const int n0 = (tloc / ktiles) * 32;
    const int t = threadIdx.x;
    __shared__ float tile[32][33];
#pragma unroll
    for (int p = 0; p < 4; p++) {
        int rr = p * 8 + (t >> 5);
        tile[rr][t & 31] = src[(size_t)(k0 + rr) * N + n0 + (t & 31)];
    }
    __syncthreads();
#pragma unroll
    for (int p = 0; p < 4; p++) {
        int rr = p * 8 + (t >> 5);
        dst[(size_t)(n0 + rr) * K + k0 + (t & 31)] = __float2bfloat16(tile[t & 31][rr]);
    }
}

// ---------------------------------------------------------------------------
// V transpose: qkv[b,n, h*192+128+c] -> vt[(b*12+h)*64+c, n]   (bf16 bits)
// ---------------------------------------------------------------------------
__global__ __launch_bounds__(256) void vt_transpose(const short* __restrict__ qkv,
                                                    short* __restrict__ vt) {
    const int bid = blockIdx.x;           // 96 bh * 64 tiles
    const int bh = bid >> 6, tau = bid & 63;
    const int b = bh / 12, h = bh % 12;
    const int ct = tau >> 5, nt = tau & 31;
    const int n0 = nt * 32, c0 = ct * 32;
    const int t = threadIdx.x;
    __shared__ short tile[32][33];
    const short* base = qkv + (size_t)(b * 1024 + n0) * 2304 + h * 192 + 128 + c0;
#pragma unroll
    for (int p = 0; p < 4; p++) {
        int rr = p * 8 + (t >> 5);
        tile[rr][t & 31] = base[(size_t)rr * 2304 + (t & 31)];
    }
    __syncthreads();
    short* ob = vt + (size_t)((b * 12 + h) * 64 + c0) * 1024 + n0;
#pragma unroll
    for (int p = 0; p < 4; p++) {
        int rr = p * 8 + (t >> 5);
        ob[(size_t)rr * 1024 + (t & 31)] = tile[t & 31][rr];
    }
}

// ---------------------------------------------------------------------------
// Flash attention, S^T formulation.  Workgroup = (64 queries, head, batch);
// 4 waves x 16 queries.  S^T = K·Q^T via MFMA(A=K, B=Q): C-layout gives each
// lane 16 scores for ONE query (q = lane&15) -> softmax is in-lane + 2 shfls.
// P^T C-regs pack to per-wave LDS as b64 runs ([q][key], stride 72), read back
// as b128 A-frags for O = P·V (V^T staged, b128 B-frags).  XCD-swizzled grid.
// ---------------------------------------------------------------------------
__global__ __launch_bounds__(256) void attn_kernel(const short* __restrict__ qkv,
                                                   const short* __restrict__ vt,
                                                   short* __restrict__ attnout) {
    // swizzle: 16 q-tiles of one (b,h) stay on one XCD (bid%8 round-robin)
    const int bid = blockIdx.x;           // 1536
    const int xcd = bid & 7, j = bid >> 3;
    const int bh = xcd * 12 + (j >> 4);
    const int qt = j & 15;
    const int b = bh / 12, hh = bh % 12;
    const int t = threadIdx.x, w = t >> 6, l = t & 63;
    const int lr = l & 15, lg = l >> 4;
    __shared__ short lK[64 * 72];          // [key][dim], stride 72
    __shared__ short lV[64 * 72];          // [dim][key], stride 72
    __shared__ short lP[4][16 * 72];       // per-wave P, [q][key], stride 72
    const int qw = qt * 64 + w * 16;

    // Q fragment (used as B operand), loaded once from global
    bf16x8 bq[2];
#pragma unroll
    for (int ks = 0; ks < 2; ks++)
        bq[ks] = *(const bf16x8*)&qkv[(size_t)(b * 1024 + qw + lr) * 2304 + hh * 192 + ks * 32 + lg * 8];

    f32x4 o[4];
#pragma unroll
    for (int dt = 0; dt < 4; dt++) o[dt] = (f32x4){0.f, 0.f, 0.f, 0.f};
    const float cexp = 0.125f * 1.44269504088896f;  // scale^2 * log2(e)
    float cm = -1.0e30f;   // running c*max, per-lane query q=lr
    float lsum = 0.f;

    for (int kt = 0; kt < 16; kt++) {
        const int key0 = kt * 64;
        __syncthreads();
#pragma unroll
        for (int i = 0; i < 2; i++) {
            int c = t + i * 256;
            int row = c >> 3, seg = c & 7;   // 64 rows x 8 chunks of 8 bf16
            *(bf16x8*)&lK[row * 72 + seg * 8] =
                *(const bf16x8*)&qkv[(size_t)(b * 1024 + key0 + row) * 2304 + hh * 192 + 64 + seg * 8];
            *(bf16x8*)&lV[row * 72 + seg * 8] =
                *(const bf16x8*)&vt[(size_t)((b * 12 + hh) * 64 + row) * 1024 + key0 + seg * 8];
        }
        __syncthreads();

        // S^T = K Q^T: lane holds S^T[key=nt*16+lg*4+r][q=lr]
        f32x4 s[4];
#pragma unroll
        for (int nt = 0; nt < 4; nt++) s[nt] = (f32x4){0.f, 0.f, 0.f, 0.f};
#pragma unroll
        for (int nt = 0; nt < 4; nt++)
#pragma unroll
            for (int ks = 0; ks < 2; ks++) {
                bf16x8 ak = *(const bf16x8*)&lK[(nt * 16 + lr) * 72 + ks * 32 + lg * 8];
                s[nt] = MFMA16(ak, bq[ks], s[nt]);
            }

        // online softmax for query q=lr: in-lane over 16, then across lg groups
        float mx = s[0][0];
#pragma unroll
        for (int nt = 0; nt < 4; nt++)
#pragma unroll
            for (int r = 0; r < 4; r++) mx = fmaxf(mx, s[nt][r]);
        mx = fmaxf(mx, __shfl_xor(mx, 16));
        mx = fmaxf(mx, __shfl_xor(mx, 32));
        const float cmn = fmaxf(cm, mx * cexp);
        const float alpha = exp2f(cm - cmn);
        cm = cmn;
        float ps = 0.f;
#pragma unroll
        for (int nt = 0; nt < 4; nt++)
#pragma unroll
            for (int r = 0; r < 4; r++) {
                float p = exp2f(s[nt][r] * cexp - cmn);
                s[nt][r] = p;
                ps += p;
            }
        ps += __shfl_xor(ps, 16);
        ps += __shfl_xor(ps, 32);
        lsum = lsum * alpha + ps;

        // pack P^T C-regs -> lP[w] as [q=lr][key], 4-key b64 runs
#pragma unroll
        for (int nt = 0; nt < 4; nt++) {
            unsigned pk0 = pack_bf2(s[nt][0], s[nt][1]);
            unsigned pk1 = pack_bf2(s[nt][2], s[nt][3]);
            *(uint2*)&lP[w][lr * 72 + nt * 16 + lg * 4] = make_uint2(pk0, pk1);
        }

        // O rescale: alpha for row q'=lg*4+r lives in lane lg*4+r
        float af[4];
#pragma unroll
        for (int r = 0; r < 4; r++) af[r] = __shfl(alpha, lg * 4 + r);
#pragma unroll
        for (int dt = 0; dt < 4; dt++)
#pragma unroll
            for (int r = 0; r < 4; r++) o[dt][r] *= af[r];

        // O += P V  (A-frag from lP b128; B-frag = V^T rows from lV b128)
#pragma unroll
        for (int kc = 0; kc < 2; kc++) {
            bf16x8 ap = *(const bf16x8*)&lP[w][lr * 72 + kc * 32 + lg * 8];
#pragma unroll
            for (int dt = 0; dt < 4; dt++) {
                bf16x8 bv = *(const bf16x8*)&lV[(dt * 16 + lr) * 72 + kc * 32 + lg * 8];
                o[dt] = MFMA16(ap, bv, o[dt]);
            }
        }
    }

    // epilogue: O[q=lg*4+r][c=dt*16+lr]; lsum for q'=lg*4+r from lane lg*4+r
    float inv[4];
#pragma unroll
    for (int r = 0; r < 4; r++) inv[r] = 1.f / __shfl(lsum, lg * 4 + r);
#pragma unroll
    for (int dt = 0; dt < 4; dt++)
#pragma unroll
        for (int r = 0; r < 4; r++)
            attnout[(size_t)(b * 1024 + qw + lg * 4 + r) * 768 + hh * 64 + dt * 16 + lr] =
                (short)f32_to_bf16_bits(o[dt][r] * inv[r]);
}

// ---------------------------------------------------------------------------
// Host
// ---------------------------------------------------------------------------
extern "C" void kernel_launch(void* const* d_in, const int* in_sizes, int n_in,
                              void* d_out, int out_size, void* d_ws, size_t ws_size,
                              hipStream_t stream) {
    const float* x    = (const float*)d_in[0];
    const float* Wqkv = (const float*)d_in[1];
    const float* bqkv = (const float*)d_in[2];
    const float* Wo   = (const float*)d_in[3];
    const float* bo   = (const float*)d_in[4];
    const float* Wfc  = (const float*)d_in[5];
    const float* bfc  = (const float*)d_in[6];
    const float* Wpr  = (const float*)d_in[7];
    const float* bpr  = (const float*)d_in[8];
    const float* g1   = (const float*)d_in[9];
    const float* b1   = (const float*)d_in[10];
    const float* g2   = (const float*)d_in[11];
    const float* b2   = (const float*)d_in[12];
    float* h = (float*)d_out;   // h lives in d_out throughout

    char* ws = (char*)d_ws;
    size_t off = 0;
    auto alloc = [&](size_t bytes) -> void* {
        void* p = ws + off;
        off += (bytes + 255) & ~(size_t)255;
        return p;
    };
    __hip_bfloat16* tQKV = (__hip_bfloat16*)alloc((size_t)2304 * 768 * 2);
    __hip_bfloat16* tO   = (__hip_bfloat16*)alloc((size_t)768 * 768 * 2);
    __hip_bfloat16* tFC  = (__hip_bfloat16*)alloc((size_t)3072 * 768 * 2);
    __hip_bfloat16* tPR  = (__hip_bfloat16*)alloc((size_t)768 * 3072 * 2);
    __hip_bfloat16* y    = (__hip_bfloat16*)alloc((size_t)8192 * 768 * 2);
    __hip_bfloat16* att  = (__hip_bfloat16*)alloc((size_t)8192 * 768 * 2);
    __hip_bfloat16* vtb  = (__hip_bfloat16*)alloc((size_t)8192 * 768 * 2);
    __hip_bfloat16* big  = (__hip_bfloat16*)alloc((size_t)8192 * 3072 * 2); // qkv & fc share
    __hip_bfloat16* qkvb = big;
    __hip_bfloat16* fcb  = big;

    hipMemcpyAsync(h, x, (size_t)8 * 1024 * 768 * 4, hipMemcpyDeviceToDevice, stream);

    for (int L = 0; L < 8; L++) {
        const float* wq = Wqkv + (size_t)L * 768 * 2304;
        const float* wo = Wo   + (size_t)L * 768 * 768;
        const float* wf = Wfc  + (size_t)L * 768 * 3072;
        const float* wp = Wpr  + (size_t)L * 3072 * 768;

        transpose_weights<<<6912, 256, 0, stream>>>(wq, wo, wf, wp, tQKV, tO, tFC, tPR);

        ln_kernel<<<8192, 256, 0, stream>>>(h, g1 + L * 768, b1 + L * 768, y);

        gemm_bt<false, false, false, true><<<dim3(18, 64), 256, 0, stream>>>(
            y, tQKV, bqkv + L * 2304, nullptr, nullptr, qkvb, 8192, 2304, 768);

        vt_transpose<<<6144, 256, 0, stream>>>((const short*)qkvb, (short*)vtb);

        attn_kernel<<<1536, 256, 0, stream>>>(
            (const short*)qkvb, (const short*)vtb, (short*)att);

        gemm_bt<true, false, true, false><<<dim3(6, 64), 256, 0, stream>>>(
            att, tO, bo + L * 768, h, h, nullptr, 8192, 768, 768);

        ln_kernel<<<8192, 256, 0, stream>>>(h, g2 + L * 768, b2 + L * 768, y);

        gemm_bt<false, true, false, true><<<dim3(24, 64), 256, 0, stream>>>(
            y, tFC, bfc + L * 3072, nullptr, nullptr, fcb, 8192, 3072, 768);

        gemm_bt<true, false, true, false><<<dim3(6, 64), 256, 0, stream>>>(
            fcb, tPR, bpr + L * 768, h, h, nullptr, 8192, 768, 3072);
    }
}

// Round 3
// 2771.953 us; speedup vs baseline: 1.1473x; 1.0711x over previous
//
#include <hip/hip_runtime.h>
#include <hip/hip_bf16.h>
#include <cstdint>
#include <cstddef>

// ---------------------------------------------------------------------------
// Transformer: L=8, B=8, N=1024, W=768, H=12, C=64.  h kept fp32 in d_out.
// All GEMMs bf16-MFMA (16x16x32), fp32 accum. LN/softmax/GELU fp32.
// ---------------------------------------------------------------------------

typedef __attribute__((ext_vector_type(8))) short bf16x8;   // 8 bf16 = 4 VGPRs
typedef __attribute__((ext_vector_type(4))) float f32x4;

#define MFMA16(a, b, c) __builtin_amdgcn_mfma_f32_16x16x32_bf16((a), (b), (c), 0, 0, 0)

__device__ __forceinline__ void gld_lds16(const void* g, void* l) {
    // async global->LDS, 16B per lane; LDS dest must be uniform_base + lane*16
    __builtin_amdgcn_global_load_lds((const __attribute__((address_space(1))) unsigned int*)g,
                                     (__attribute__((address_space(3))) unsigned int*)l,
                                     16, 0, 0);
}

__device__ __forceinline__ unsigned short f32_to_bf16_bits(float f) {
    unsigned u = __builtin_bit_cast(unsigned, f);
    u += 0x7fffu + ((u >> 16) & 1u);      // RNE; inputs are finite
    return (unsigned short)(u >> 16);
}

__device__ __forceinline__ unsigned pack_bf2(float a, float b) {
    return (unsigned)f32_to_bf16_bits(a) | ((unsigned)f32_to_bf16_bits(b) << 16);
}

// ---------------------------------------------------------------------------
// GEMM: C[M,N] = A[M,K](bf16) @ Bt[N,K]^T(bf16) + bias; optional residual(fp32,
// in-place ok), exact GELU, fp32 and/or bf16 outputs.  M == 8192 (64 m-tiles),
// N % 128 == 0, K % 64 == 0.  1D grid = 64 * (N/128) blocks.
// XCD swizzle: bid&7 = XCD; 8 contiguous m-tiles per XCD; n fastest within.
// BK=64 as twin 128x32 buffers (keeps 64B row stride for bank-friendly b128
// frag reads AND the global_load_lds uniform-base+lane*16 contiguity rule).
// ---------------------------------------------------------------------------
template <bool RES, bool GELU, bool WF, bool WH>
__global__ __launch_bounds__(256) void gemm_bt(const __hip_bfloat16* __restrict__ A,
                                               const __hip_bfloat16* __restrict__ Bt,
                                               const float* __restrict__ bias,
                                               const float* __restrict__ res,
                                               float* __restrict__ outf,
                                               __hip_bfloat16* __restrict__ outh,
                                               int N, int K) {
    __shared__ __hip_bfloat16 lA0[128 * 32], lA1[128 * 32];
    __shared__ __hip_bfloat16 lB0[128 * 32], lB1[128 * 32];
    const int t = threadIdx.x;
    const int w = t >> 6, l = t & 63;
    const int lr = l & 15, lg = l >> 4;
    // XCD-aware decode: 64 m-tiles total, 8 per XCD
    const int bid = blockIdx.x;
    const int xcd = bid & 7;
    const int local = bid >> 3;
    const int m0 = (xcd * 8 + (local & 7)) * 128;
    const int n0 = (local >> 3) * 128;
    const int wm = (w & 1) * 64, wn = (w >> 1) * 64;

    f32x4 acc[4][4];
#pragma unroll
    for (int i = 0; i < 4; i++)
#pragma unroll
        for (int j = 0; j < 4; j++) acc[i][j] = (f32x4){0.f, 0.f, 0.f, 0.f};

    for (int k0 = 0; k0 < K; k0 += 64) {
        __syncthreads();
#pragma unroll
        for (int i = 0; i < 2; i++) {
            int c = t + i * 256;            // 512 chunks of 16B per 8KB tile
            int row = c >> 2, seg = c & 3;  // row-major [128][32] bf16
            const size_t ab = (size_t)(m0 + row) * K + k0 + seg * 8;
            const size_t bb = (size_t)(n0 + row) * K + k0 + seg * 8;
            gld_lds16(&A[ab],       &lA0[c * 8]);
            gld_lds16(&A[ab + 32],  &lA1[c * 8]);
            gld_lds16(&Bt[bb],      &lB0[c * 8]);
            gld_lds16(&Bt[bb + 32], &lB1[c * 8]);
        }
        __syncthreads();
#pragma unroll
        for (int hh = 0; hh < 2; hh++) {
            const __hip_bfloat16* sA = hh ? lA1 : lA0;
            const __hip_bfloat16* sB = hh ? lB1 : lB0;
            bf16x8 af[4], bfr[4];
#pragma unroll
            for (int mt = 0; mt < 4; mt++)
                af[mt] = *(const bf16x8*)&sA[(wm + mt * 16 + lr) * 32 + lg * 8];
#pragma unroll
            for (int nt = 0; nt < 4; nt++)
                bfr[nt] = *(const bf16x8*)&sB[(wn + nt * 16 + lr) * 32 + lg * 8];
#pragma unroll
            for (int mt = 0; mt < 4; mt++)
#pragma unroll
                for (int nt = 0; nt < 4; nt++)
                    acc[mt][nt] = MFMA16(af[mt], bfr[nt], acc[mt][nt]);
        }
    }

    // epilogue: C/D layout col=lane&15, row=(lane>>4)*4+reg  [m89/m91 verified]
#pragma unroll
    for (int nt = 0; nt < 4; nt++) {
        const int col = n0 + wn + nt * 16 + lr;
        const float bv = bias[col];
#pragma unroll
        for (int mt = 0; mt < 4; mt++) {
#pragma unroll
            for (int r = 0; r < 4; r++) {
                const int row = m0 + wm + mt * 16 + lg * 4 + r;
                const size_t idx = (size_t)row * N + col;
                float v = acc[mt][nt][r] + bv;
                if (RES) v += res[idx];
                if (GELU) v = 0.5f * v * (1.f + erff(v * 0.70710678118654752f));
                if (WF) outf[idx] = v;
                if (WH) outh[idx] = __float2bfloat16(v);
            }
        }
    }
}

// ---------------------------------------------------------------------------
// LayerNorm over W=768: one WAVE per row (4 rows/block), float4 loads, no LDS.
// fp32 in, bf16 out (affine).  grid = 2048.
// ---------------------------------------------------------------------------
__global__ __launch_bounds__(256) void ln_kernel(const float* __restrict__ h,
                                                 const float* __restrict__ g,
                                                 const float* __restrict__ b,
                                                 __hip_bfloat16* __restrict__ y) {
    const int t = threadIdx.x;
    const int w = t >> 6, l = t & 63;
    const int row = blockIdx.x * 4 + w;
    const float4* hr = (const float4*)(h + (size_t)row * 768);
    const float4* g4 = (const float4*)g;
    const float4* b4 = (const float4*)b;
    float4 x[3];
    float s = 0.f, q = 0.f;
#pragma unroll
    for (int j = 0; j < 3; j++) {
        x[j] = hr[l + j * 64];
        s += x[j].x + x[j].y + x[j].z + x[j].w;
        q += x[j].x * x[j].x + x[j].y * x[j].y + x[j].z * x[j].z + x[j].w * x[j].w;
    }
#pragma unroll
    for (int d = 1; d < 64; d <<= 1) {
        s += __shfl_xor(s, d);
        q += __shfl_xor(q, d);
    }
    const float mean = s * (1.f / 768.f);
    const float var = q * (1.f / 768.f) - mean * mean;
    const float rs = rsqrtf(var + 1e-5f);
    uint2* yr = (uint2*)(y + (size_t)row * 768);
#pragma unroll
    for (int j = 0; j < 3; j++) {
        const float4 gg = g4[l + j * 64], bb = b4[l + j * 64];
        float o0 = (x[j].x - mean) * rs * gg.x + bb.x;
        float o1 = (x[j].y - mean) * rs * gg.y + bb.y;
        float o2 = (x[j].z - mean) * rs * gg.z + bb.z;
        float o3 = (x[j].w - mean) * rs * gg.w + bb.w;
        yr[l + j * 64] = make_uint2(pack_bf2(o0, o1), pack_bf2(o2, o3));
    }
}

// ---------------------------------------------------------------------------
// Per-layer weight transpose+convert: W[K,N] fp32 -> Wt[N,K] bf16 (4 matrices).
// ---------------------------------------------------------------------------
__global__ __launch_bounds__(256) void transpose_weights(const float* __restrict__ sq,
                                                         const float* __restrict__ so,
                                                         const float* __restrict__ sf,
                                                         const float* __restrict__ sp,
                                                         __hip_bfloat16* __restrict__ dq,
                                                         __hip_bfloat16* __restrict__ dO,
                                                         __hip_bfloat16* __restrict__ df,
                                                         __hip_bfloat16* __restrict__ dp) {
    const int bid = blockIdx.x;
    const float* src;
    __hip_bfloat16* dst;
    int K, N, tloc;
    if (bid < 1728)      { src = sq; dst = dq; K = 768;  N = 2304; tloc = bid; }
    else if (bid < 2304) { src = so; dst = dO; K = 768;  N = 768;  tloc = bid - 1728; }
    else if (bid < 4608) { src = sf; dst = df; K = 768;  N = 3072; tloc = bid - 2304; }
    else                 { src = sp; dst = dp; K = 3072; N = 768;  tloc = bid - 4608; }
    const int ktiles = K / 32;
    const int k0 = (tloc % ktiles) * 32;
    const int n0 = (tloc / ktiles) * 32;
    const int t = threadIdx.x;
    __shared__ float tile[32][33];
#pragma unroll
    for (int p = 0; p < 4; p++) {
        int rr = p * 8 + (t >> 5);
        tile[rr][t & 31] = src[(size_t)(k0 + rr) * N + n0 + (t & 31)];
    }
    __syncthreads();
#pragma unroll
    for (int p = 0; p < 4; p++) {
        int rr = p * 8 + (t >> 5);
        dst[(size_t)(n0 + rr) * K + k0 + (t & 31)] = __float2bfloat16(tile[t & 31][rr]);
    }
}

// ---------------------------------------------------------------------------
// V transpose: qkv[b,n, h*192+128+c] -> vt[(b*12+h)*64+c, n]   (bf16 bits)
// ---------------------------------------------------------------------------
__global__ __launch_bounds__(256) void vt_transpose(const short* __restrict__ qkv,
                                                    short* __restrict__ vt) {
    const int bid = blockIdx.x;           // 96 bh * 64 tiles
    const int bh = bid >> 6, tau = bid & 63;
    const int b = bh / 12, h = bh % 12;
    const int ct = tau >> 5, nt = tau & 31;
    const int n0 = nt * 32, c0 = ct * 32;
    const int t = threadIdx.x;
    __shared__ short tile[32][33];
    const short* base = qkv + (size_t)(b * 1024 + n0) * 2304 + h * 192 + 128 + c0;
#pragma unroll
    for (int p = 0; p < 4; p++) {
        int rr = p * 8 + (t >> 5);
        tile[rr][t & 31] = base[(size_t)rr * 2304 + (t & 31)];
    }
    __syncthreads();
    short* ob = vt + (size_t)((b * 12 + h) * 64 + c0) * 1024 + n0;
#pragma unroll
    for (int p = 0; p < 4; p++) {
        int rr = p * 8 + (t >> 5);
        ob[(size_t)rr * 1024 + (t & 31)] = tile[t & 31][rr];
    }
}

// ---------------------------------------------------------------------------
// Flash attention, S^T formulation.  Workgroup = (64 queries, head, batch);
// 4 waves x 16 queries.  S^T = K·Q^T via MFMA(A=K, B=Q): C-layout gives each
// lane 16 scores for ONE query (q = lane&15) -> softmax is in-lane + 2 shfls.
// P^T C-regs pack to per-wave LDS as b64 runs ([q][key], stride 72), read back
// as b128 A-frags for O = P·V (V^T staged, b128 B-frags).  XCD-swizzled grid.
// ---------------------------------------------------------------------------
__global__ __launch_bounds__(256) void attn_kernel(const short* __restrict__ qkv,
                                                   const short* __restrict__ vt,
                                                   short* __restrict__ attnout) {
    // swizzle: 16 q-tiles of one (b,h) stay on one XCD (bid%8 round-robin)
    const int bid = blockIdx.x;           // 1536
    const int xcd = bid & 7, j = bid >> 3;
    const int bh = xcd * 12 + (j >> 4);
    const int qt = j & 15;
    const int b = bh / 12, hh = bh % 12;
    const int t = threadIdx.x, w = t >> 6, l = t & 63;
    const int lr = l & 15, lg = l >> 4;
    __shared__ short lK[64 * 72];          // [key][dim], stride 72
    __shared__ short lV[64 * 72];          // [dim][key], stride 72
    __shared__ short lP[4][16 * 72];       // per-wave P, [q][key], stride 72
    const int qw = qt * 64 + w * 16;

    // Q fragment (used as B operand), loaded once from global
    bf16x8 bq[2];
#pragma unroll
    for (int ks = 0; ks < 2; ks++)
        bq[ks] = *(const bf16x8*)&qkv[(size_t)(b * 1024 + qw + lr) * 2304 + hh * 192 + ks * 32 + lg * 8];

    f32x4 o[4];
#pragma unroll
    for (int dt = 0; dt < 4; dt++) o[dt] = (f32x4){0.f, 0.f, 0.f, 0.f};
    const float cexp = 0.125f * 1.44269504088896f;  // scale^2 * log2(e)
    float cm = -1.0e30f;   // running c*max, per-lane query q=lr
    float lsum = 0.f;

    for (int kt = 0; kt < 16; kt++) {
        const int key0 = kt * 64;
        __syncthreads();
#pragma unroll
        for (int i = 0; i < 2; i++) {
            int c = t + i * 256;
            int row = c >> 3, seg = c & 7;   // 64 rows x 8 chunks of 8 bf16
            *(bf16x8*)&lK[row * 72 + seg * 8] =
                *(const bf16x8*)&qkv[(size_t)(b * 1024 + key0 + row) * 2304 + hh * 192 + 64 + seg * 8];
            *(bf16x8*)&lV[row * 72 + seg * 8] =
                *(const bf16x8*)&vt[(size_t)((b * 12 + hh) * 64 + row) * 1024 + key0 + seg * 8];
        }
        __syncthreads();

        // S^T = K Q^T: lane holds S^T[key=nt*16+lg*4+r][q=lr]
        f32x4 s[4];
#pragma unroll
        for (int nt = 0; nt < 4; nt++) s[nt] = (f32x4){0.f, 0.f, 0.f, 0.f};
#pragma unroll
        for (int nt = 0; nt < 4; nt++)
#pragma unroll
            for (int ks = 0; ks < 2; ks++) {
                bf16x8 ak = *(const bf16x8*)&lK[(nt * 16 + lr) * 72 + ks * 32 + lg * 8];
                s[nt] = MFMA16(ak, bq[ks], s[nt]);
            }

        // online softmax for query q=lr: in-lane over 16, then across lg groups
        float mx = s[0][0];
#pragma unroll
        for (int nt = 0; nt < 4; nt++)
#pragma unroll
            for (int r = 0; r < 4; r++) mx = fmaxf(mx, s[nt][r]);
        mx = fmaxf(mx, __shfl_xor(mx, 16));
        mx = fmaxf(mx, __shfl_xor(mx, 32));
        const float cmn = fmaxf(cm, mx * cexp);
        const float alpha = exp2f(cm - cmn);
        cm = cmn;
        float ps = 0.f;
#pragma unroll
        for (int nt = 0; nt < 4; nt++)
#pragma unroll
            for (int r = 0; r < 4; r++) {
                float p = exp2f(s[nt][r] * cexp - cmn);
                s[nt][r] = p;
                ps += p;
            }
        ps += __shfl_xor(ps, 16);
        ps += __shfl_xor(ps, 32);
        lsum = lsum * alpha + ps;

        // pack P^T C-regs -> lP[w] as [q=lr][key], 4-key b64 runs
#pragma unroll
        for (int nt = 0; nt < 4; nt++) {
            unsigned pk0 = pack_bf2(s[nt][0], s[nt][1]);
            unsigned pk1 = pack_bf2(s[nt][2], s[nt][3]);
            *(uint2*)&lP[w][lr * 72 + nt * 16 + lg * 4] = make_uint2(pk0, pk1);
        }

        // O rescale: alpha for row q'=lg*4+r lives in lane lg*4+r
        float af[4];
#pragma unroll
        for (int r = 0; r < 4; r++) af[r] = __shfl(alpha, lg * 4 + r);
#pragma unroll
        for (int dt = 0; dt < 4; dt++)
#pragma unroll
            for (int r = 0; r < 4; r++) o[dt][r] *= af[r];

        // O += P V  (A-frag from lP b128; B-frag = V^T rows from lV b128)
#pragma unroll
        for (int kc = 0; kc < 2; kc++) {
            bf16x8 ap = *(const bf16x8*)&lP[w][lr * 72 + kc * 32 + lg * 8];
#pragma unroll
            for (int dt = 0; dt < 4; dt++) {
                bf16x8 bv = *(const bf16x8*)&lV[(dt * 16 + lr) * 72 + kc * 32 + lg * 8];
                o[dt] = MFMA16(ap, bv, o[dt]);
            }
        }
    }

    // epilogue: O[q=lg*4+r][c=dt*16+lr]; lsum for q'=lg*4+r from lane lg*4+r
    float inv[4];
#pragma unroll
    for (int r = 0; r < 4; r++) inv[r] = 1.f / __shfl(lsum, lg * 4 + r);
#pragma unroll
    for (int dt = 0; dt < 4; dt++)
#pragma unroll
        for (int r = 0; r < 4; r++)
            attnout[(size_t)(b * 1024 + qw + lg * 4 + r) * 768 + hh * 64 + dt * 16 + lr] =
                (short)f32_to_bf16_bits(o[dt][r] * inv[r]);
}

// ---------------------------------------------------------------------------
// Host
// ---------------------------------------------------------------------------
extern "C" void kernel_launch(void* const* d_in, const int* in_sizes, int n_in,
                              void* d_out, int out_size, void* d_ws, size_t ws_size,
                              hipStream_t stream) {
    const float* x    = (const float*)d_in[0];
    const float* Wqkv = (const float*)d_in[1];
    const float* bqkv = (const float*)d_in[2];
    const float* Wo   = (const float*)d_in[3];
    const float* bo   = (const float*)d_in[4];
    const float* Wfc  = (const float*)d_in[5];
    const float* bfc  = (const float*)d_in[6];
    const float* Wpr  = (const float*)d_in[7];
    const float* bpr  = (const float*)d_in[8];
    const float* g1   = (const float*)d_in[9];
    const float* b1   = (const float*)d_in[10];
    const float* g2   = (const float*)d_in[11];
    const float* b2   = (const float*)d_in[12];
    float* h = (float*)d_out;   // h lives in d_out throughout

    char* ws = (char*)d_ws;
    size_t off = 0;
    auto alloc = [&](size_t bytes) -> void* {
        void* p = ws + off;
        off += (bytes + 255) & ~(size_t)255;
        return p;
    };
    __hip_bfloat16* tQKV = (__hip_bfloat16*)alloc((size_t)2304 * 768 * 2);
    __hip_bfloat16* tO   = (__hip_bfloat16*)alloc((size_t)768 * 768 * 2);
    __hip_bfloat16* tFC  = (__hip_bfloat16*)alloc((size_t)3072 * 768 * 2);
    __hip_bfloat16* tPR  = (__hip_bfloat16*)alloc((size_t)768 * 3072 * 2);
    __hip_bfloat16* y    = (__hip_bfloat16*)alloc((size_t)8192 * 768 * 2);
    __hip_bfloat16* att  = (__hip_bfloat16*)alloc((size_t)8192 * 768 * 2);
    __hip_bfloat16* vtb  = (__hip_bfloat16*)alloc((size_t)8192 * 768 * 2);
    __hip_bfloat16* big  = (__hip_bfloat16*)alloc((size_t)8192 * 3072 * 2); // qkv & fc share
    __hip_bfloat16* qkvb = big;
    __hip_bfloat16* fcb  = big;

    hipMemcpyAsync(h, x, (size_t)8 * 1024 * 768 * 4, hipMemcpyDeviceToDevice, stream);

    for (int L = 0; L < 8; L++) {
        const float* wq = Wqkv + (size_t)L * 768 * 2304;
        const float* wo = Wo   + (size_t)L * 768 * 768;
        const float* wf = Wfc  + (size_t)L * 768 * 3072;
        const float* wp = Wpr  + (size_t)L * 3072 * 768;

        transpose_weights<<<6912, 256, 0, stream>>>(wq, wo, wf, wp, tQKV, tO, tFC, tPR);

        ln_kernel<<<2048, 256, 0, stream>>>(h, g1 + L * 768, b1 + L * 768, y);

        gemm_bt<false, false, false, true><<<18 * 64, 256, 0, stream>>>(
            y, tQKV, bqkv + L * 2304, nullptr, nullptr, qkvb, 2304, 768);

        vt_transpose<<<6144, 256, 0, stream>>>((const short*)qkvb, (short*)vtb);

        attn_kernel<<<1536, 256, 0, stream>>>(
            (const short*)qkvb, (const short*)vtb, (short*)att);

        gemm_bt<true, false, true, false><<<6 * 64, 256, 0, stream>>>(
            att, tO, bo + L * 768, h, h, nullptr, 768, 768);

        ln_kernel<<<2048, 256, 0, stream>>>(h, g2 + L * 768, b2 + L * 768, y);

        gemm_bt<false, true, false, true><<<24 * 64, 256, 0, stream>>>(
            y, tFC, bfc + L * 3072, nullptr, nullptr, fcb, 3072, 768);

        gemm_bt<true, false, true, false><<<6 * 64, 256, 0, stream>>>(
            fcb, tPR, bpr + L * 768, h, h, nullptr, 768, 3072);
    }
}